// Round 2
// baseline (494.933 us; speedup 1.0000x reference)
//
#include <hip/hip_runtime.h>

// Problem constants
#define NUM_EMB 1024
#define EMB_DIM 256
#define BATCH   32
#define HW      1024
#define Z_ELEMS (BATCH*EMB_DIM*HW)   // 8388608
#define LOSS_OFF Z_ELEMS
#define IDX_OFF (Z_ELEMS+1)

// ws layout (floats): [0] loss acc, [16..16+1024) cnorm, [2048..2048+32768) znorm
#define WS_CNORM_OFF 16
#define WS_ZNORM_OFF 2048

// ---------------------------------------------------------------------------
// K0: cnorm[k] = sum_d cb[k][d]^2 via numpy's exact pairwise tree (fp32,
// squares rounded separately, no fma contraction). Also zero loss acc.
__global__ __launch_bounds__(256) void k_cnorm(const float* __restrict__ cb,
                                               float* __restrict__ ws) {
    int k = blockIdx.x * 256 + threadIdx.x;
    if (k == 0) ws[0] = 0.0f;
    const float* row = cb + (size_t)k * EMB_DIM;
    float half[2];
#pragma unroll
    for (int h = 0; h < 2; ++h) {
        const float* a = row + h * 128;
        float r[8];
#pragma unroll
        for (int j = 0; j < 8; ++j) r[j] = __fmul_rn(a[j], a[j]);
        for (int i = 8; i < 128; i += 8)
#pragma unroll
            for (int j = 0; j < 8; ++j)
                r[j] = __fadd_rn(r[j], __fmul_rn(a[i + j], a[i + j]));
        half[h] = __fadd_rn(__fadd_rn(__fadd_rn(r[0], r[1]), __fadd_rn(r[2], r[3])),
                            __fadd_rn(__fadd_rn(r[4], r[5]), __fadd_rn(r[6], r[7])));
    }
    ws[WS_CNORM_OFF + k] = __fadd_rn(half[0], half[1]);
}

// ---------------------------------------------------------------------------
// K0b: znorm[n] = sum_d z[n][d]^2, same numpy pairwise tree. Query n=(b,p),
// element d lives at z[b*D*HW + d*HW + p] -> lane-consecutive p = coalesced.
__global__ __launch_bounds__(256) void k_znorm(const float* __restrict__ z,
                                               float* __restrict__ ws) {
    int n = blockIdx.x * 256 + threadIdx.x;
    int b = n >> 10, p = n & 1023;
    const float* base = z + (size_t)b * EMB_DIM * HW + p;
    float half[2];
#pragma unroll
    for (int h = 0; h < 2; ++h) {
        float r[8];
#pragma unroll
        for (int j = 0; j < 8; ++j) {
            float v = base[(size_t)(h * 128 + j) * HW];
            r[j] = __fmul_rn(v, v);
        }
        for (int i = 8; i < 128; i += 8)
#pragma unroll
            for (int j = 0; j < 8; ++j) {
                float v = base[(size_t)(h * 128 + i + j) * HW];
                r[j] = __fadd_rn(r[j], __fmul_rn(v, v));
            }
        half[h] = __fadd_rn(__fadd_rn(__fadd_rn(r[0], r[1]), __fadd_rn(r[2], r[3])),
                            __fadd_rn(__fadd_rn(r[4], r[5]), __fadd_rn(r[6], r[7])));
    }
    ws[WS_ZNORM_OFF + n] = __fadd_rn(half[0], half[1]);
}

// ---------------------------------------------------------------------------
// K1: distance argmin, bit-replicating the reference fp32 rounding:
//   d = fl( fl(z2 + c2) - fl(2*dot) ),  dot = serial ascending-k fma (sgemm order)
// Ties broken by smallest index (numpy argmin first-occurrence).
#define MT 64
#define KC 256
#define DC 32
#define CPAD 260

__global__ __launch_bounds__(128) void k_argmin(const float* __restrict__ z,
                                                const float* __restrict__ cb,
                                                const float* __restrict__ ws,
                                                float* __restrict__ out) {
    __shared__ __attribute__((aligned(16))) float z_buf[DC * MT];    // 8 KB
    __shared__ __attribute__((aligned(16))) float c_buf[DC * CPAD];  // 33.3 KB

    const int tid = threadIdx.x;
    const int tx = tid & 15;      // k direction
    const int ty = tid >> 4;      // m direction (0..7)
    const int b  = blockIdx.y;
    const int p0 = blockIdx.x * MT;

    const float* zb = z + (size_t)b * EMB_DIM * HW + p0;
    const float* cn = ws + WS_CNORM_OFF;
    const float* zn = ws + WS_ZNORM_OFF + b * HW + p0;

    float z2[8];
#pragma unroll
    for (int a = 0; a < 8; ++a)
        z2[a] = zn[((a >> 2) << 5) + ty * 4 + (a & 3)];

    float minv[8];
    int   mini[8];
#pragma unroll
    for (int a = 0; a < 8; ++a) { minv[a] = 3.402823466e+38f; mini[a] = 0; }

#pragma unroll 1
    for (int kc = 0; kc < NUM_EMB / KC; ++kc) {
        const int k0 = kc * KC;
        float acc[8][16];
#pragma unroll
        for (int a = 0; a < 8; ++a)
#pragma unroll
            for (int q = 0; q < 16; ++q) acc[a][q] = 0.0f;

#pragma unroll 1
        for (int dc = 0; dc < EMB_DIM / DC; ++dc) {
            __syncthreads();
#pragma unroll
            for (int pass = 0; pass < 4; ++pass) {
                int idx = pass * 128 + tid;
                int row = idx >> 4;
                int col = (idx & 15) << 2;
                float4 v = *(const float4*)(zb + (size_t)(dc * DC + row) * HW + col);
                *(float4*)(z_buf + row * MT + col) = v;
            }
#pragma unroll
            for (int pass = 0; pass < 16; ++pass) {
                int idx = pass * 128 + tid;
                int kk = idx >> 3;
                int seg = idx & 7;
                float4 v = *(const float4*)(cb + (size_t)(k0 + kk) * EMB_DIM + dc * DC + seg * 4);
                c_buf[(seg * 4 + 0) * CPAD + kk] = v.x;
                c_buf[(seg * 4 + 1) * CPAD + kk] = v.y;
                c_buf[(seg * 4 + 2) * CPAD + kk] = v.z;
                c_buf[(seg * 4 + 3) * CPAD + kk] = v.w;
            }
            __syncthreads();

#pragma unroll 2
            for (int d = 0; d < DC; ++d) {
                float4 za = *(const float4*)(z_buf + d * MT + ty * 4);
                float4 zc = *(const float4*)(z_buf + d * MT + 32 + ty * 4);
                float zf[8] = {za.x, za.y, za.z, za.w, zc.x, zc.y, zc.z, zc.w};
                float cf[16];
#pragma unroll
                for (int j = 0; j < 4; ++j) {
                    float4 cv = *(const float4*)(c_buf + d * CPAD + j * 64 + tx * 4);
                    cf[j * 4 + 0] = cv.x; cf[j * 4 + 1] = cv.y;
                    cf[j * 4 + 2] = cv.z; cf[j * 4 + 3] = cv.w;
                }
#pragma unroll
                for (int a = 0; a < 8; ++a)
#pragma unroll
                    for (int q = 0; q < 16; ++q)
                        acc[a][q] = fmaf(zf[a], cf[q], acc[a][q]);
            }
        }
        // fold chunk into running argmin with reference rounding
        float c2[16];
#pragma unroll
        for (int q = 0; q < 16; ++q)
            c2[q] = cn[k0 + (q >> 2) * 64 + tx * 4 + (q & 3)];
#pragma unroll
        for (int a = 0; a < 8; ++a) {
#pragma unroll
            for (int q = 0; q < 16; ++q) {   // q ascending => kg ascending (per tx)
                int kg = k0 + (q >> 2) * 64 + tx * 4 + (q & 3);
                float t1 = __fadd_rn(z2[a], c2[q]);
                float s  = __fadd_rn(t1, __fmul_rn(-2.0f, acc[a][q]));
                if (s < minv[a]) { minv[a] = s; mini[a] = kg; }  // strict <: first index wins
            }
        }
    }

    // cross-tx reduction (reuse c_buf), ties -> smallest index
    __syncthreads();
    float* rv = c_buf;
    int*   ri = (int*)(c_buf + 1024);
#pragma unroll
    for (int a = 0; a < 8; ++a) {
        int m = ((a >> 2) << 5) + ty * 4 + (a & 3);
        rv[m * 16 + tx] = minv[a];
        ri[m * 16 + tx] = mini[a];
    }
    __syncthreads();
    if (tid < MT) {
        int m = tid;
        float bv = rv[m * 16];
        int   bi = ri[m * 16];
#pragma unroll
        for (int j = 1; j < 16; ++j) {
            float v = rv[m * 16 + j];
            int   i2 = ri[m * 16 + j];
            if (v < bv || (v == bv && i2 < bi)) { bv = v; bi = i2; }
        }
        out[IDX_OFF + (size_t)b * HW + p0 + m] = (float)bi;
    }
}

// ---------------------------------------------------------------------------
// K2: gather z_q, straight-through out = fl(z + fl(z_q - z)), loss partial sums
__global__ __launch_bounds__(256) void k_gather(const float* __restrict__ z,
                                                const float* __restrict__ cb,
                                                float* __restrict__ out,
                                                float* __restrict__ ws) {
    __shared__ int   s_idx[64];
    __shared__ float s_red[4];
    const int tid = threadIdx.x;
    const int b  = blockIdx.x >> 4;
    const int p0 = (blockIdx.x & 15) * 64;

    if (tid < 64)
        s_idx[tid] = (int)out[IDX_OFF + (size_t)b * HW + p0 + tid];
    __syncthreads();

    const int p = tid & 63;
    const int cbase = tid >> 6;
    const int r = s_idx[p];
    const float* zrow = z   + (size_t)b * EMB_DIM * HW + p0 + p;
    float*       orow = out + (size_t)b * EMB_DIM * HW + p0 + p;
    const float* crow = cb  + (size_t)r * EMB_DIM;

    float acc = 0.0f;
#pragma unroll 4
    for (int it = 0; it < 64; ++it) {
        int c = it * 4 + cbase;
        float zq = crow[c];
        float zv = zrow[(size_t)c * HW];
        float d  = zq - zv;
        orow[(size_t)c * HW] = zv + d;
        acc += d * d;
    }
#pragma unroll
    for (int off = 32; off > 0; off >>= 1) acc += __shfl_down(acc, off, 64);
    if ((tid & 63) == 0) s_red[tid >> 6] = acc;
    __syncthreads();
    if (tid == 0) atomicAdd(ws, s_red[0] + s_red[1] + s_red[2] + s_red[3]);
}

// ---------------------------------------------------------------------------
__global__ void k_final(const float* __restrict__ ws, float* __restrict__ out) {
    out[LOSS_OFF] = 1.25f * (ws[0] * (1.0f / 8388608.0f));
}

// ---------------------------------------------------------------------------
extern "C" void kernel_launch(void* const* d_in, const int* in_sizes, int n_in,
                              void* d_out, int out_size, void* d_ws, size_t ws_size,
                              hipStream_t stream) {
    const float* z  = (const float*)d_in[0];
    const float* cb = (const float*)d_in[1];
    float* out = (float*)d_out;
    float* ws  = (float*)d_ws;

    k_cnorm <<<NUM_EMB / 256, 256, 0, stream>>>(cb, ws);
    k_znorm <<<BATCH * HW / 256, 256, 0, stream>>>(z, ws);
    k_argmin<<<dim3(HW / MT, BATCH), 128, 0, stream>>>(z, cb, ws, out);
    k_gather<<<BATCH * (HW / 64), 256, 0, stream>>>(z, cb, out, ws);
    k_final <<<1, 1, 0, stream>>>(ws, out);
}

// Round 3
// 352.426 us; speedup vs baseline: 1.4044x; 1.4044x over previous
//
#include <hip/hip_runtime.h>

// Problem constants
#define NUM_EMB 1024
#define EMB_DIM 256
#define BATCH   32
#define HW      1024
#define Z_ELEMS (BATCH*EMB_DIM*HW)   // 8388608
#define LOSS_OFF Z_ELEMS
#define IDX_OFF (Z_ELEMS+1)

// ws layout (floats): [0] loss acc, [16..16+1024) cnorm, [2048..2048+32768) znorm
#define WS_CNORM_OFF 16
#define WS_ZNORM_OFF 2048
// Partial argmin results are staged in the z-region of `out` (overwritten later
// by k_gather): vals (float) at out[0..65536), idx (int) at ((int*)out)[65536..131072)

typedef float v2f __attribute__((ext_vector_type(2)));

// ---------------------------------------------------------------------------
// K0: cnorm[k] = sum_d cb[k][d]^2 via numpy's exact pairwise tree (fp32,
// squares rounded separately, no fma contraction). Also zero loss acc.
__global__ __launch_bounds__(256) void k_cnorm(const float* __restrict__ cb,
                                               float* __restrict__ ws) {
    int k = blockIdx.x * 256 + threadIdx.x;
    if (k == 0) ws[0] = 0.0f;
    const float* row = cb + (size_t)k * EMB_DIM;
    float half[2];
#pragma unroll
    for (int h = 0; h < 2; ++h) {
        const float* a = row + h * 128;
        float r[8];
#pragma unroll
        for (int j = 0; j < 8; ++j) r[j] = __fmul_rn(a[j], a[j]);
        for (int i = 8; i < 128; i += 8)
#pragma unroll
            for (int j = 0; j < 8; ++j)
                r[j] = __fadd_rn(r[j], __fmul_rn(a[i + j], a[i + j]));
        half[h] = __fadd_rn(__fadd_rn(__fadd_rn(r[0], r[1]), __fadd_rn(r[2], r[3])),
                            __fadd_rn(__fadd_rn(r[4], r[5]), __fadd_rn(r[6], r[7])));
    }
    ws[WS_CNORM_OFF + k] = __fadd_rn(half[0], half[1]);
}

// ---------------------------------------------------------------------------
// K0b: znorm[n] = sum_d z[n][d]^2, same numpy pairwise tree.
__global__ __launch_bounds__(256) void k_znorm(const float* __restrict__ z,
                                               float* __restrict__ ws) {
    int n = blockIdx.x * 256 + threadIdx.x;
    int b = n >> 10, p = n & 1023;
    const float* base = z + (size_t)b * EMB_DIM * HW + p;
    float half[2];
#pragma unroll
    for (int h = 0; h < 2; ++h) {
        float r[8];
#pragma unroll
        for (int j = 0; j < 8; ++j) {
            float v = base[(size_t)(h * 128 + j) * HW];
            r[j] = __fmul_rn(v, v);
        }
        for (int i = 8; i < 128; i += 8)
#pragma unroll
            for (int j = 0; j < 8; ++j) {
                float v = base[(size_t)(h * 128 + i + j) * HW];
                r[j] = __fadd_rn(r[j], __fmul_rn(v, v));
            }
        half[h] = __fadd_rn(__fadd_rn(__fadd_rn(r[0], r[1]), __fadd_rn(r[2], r[3])),
                            __fadd_rn(__fadd_rn(r[4], r[5]), __fadd_rn(r[6], r[7])));
    }
    ws[WS_ZNORM_OFF + n] = __fadd_rn(half[0], half[1]);
}

// ---------------------------------------------------------------------------
// K1: distance argmin over a 512-code half, reference fp32 rounding:
//   d = fl( fl(z2 + c2) - fl(2*dot) ),  dot = serial ascending-d fma per (n,k)
// (v_pk_fma_f32 packs two independent k-chains; each chain stays serial.)
// Block 256 thr: tx=tid&15 (16 k each), ty=tid>>4 (4 m each). MT=64, KC=256,
// DC=16 (LDS 20.7 KB -> 4 blocks/CU; grid 1024 -> 16 waves/CU).
#define MT 64
#define KC 256
#define DC 16
#define CPAD 260

__global__ __launch_bounds__(256, 4) void k_argmin(const float* __restrict__ z,
                                                   const float* __restrict__ cb,
                                                   const float* __restrict__ ws,
                                                   float* __restrict__ out) {
    __shared__ __attribute__((aligned(16))) float z_buf[DC * MT];    // 4 KB
    __shared__ __attribute__((aligned(16))) float c_buf[DC * CPAD];  // 16.6 KB

    const int tid = threadIdx.x;
    const int tx = tid & 15;
    const int ty = tid >> 4;          // 0..15
    const int b  = blockIdx.y;
    const int p0 = blockIdx.x * MT;
    const int kh = blockIdx.z;        // 0/1 k-half
    const int kbase = kh * 512;

    const float* zb = z + (size_t)b * EMB_DIM * HW + p0;
    const float* cn = ws + WS_CNORM_OFF;
    const float* zn = ws + WS_ZNORM_OFF + b * HW + p0;

    float z2[4];
#pragma unroll
    for (int a = 0; a < 4; ++a) z2[a] = zn[ty * 4 + a];

    float minv[4];
    int   mini[4];
#pragma unroll
    for (int a = 0; a < 4; ++a) { minv[a] = 3.402823466e+38f; mini[a] = 0; }

    // staging coords (loop-invariant)
    const int zrow = tid >> 4;            // 0..15
    const int zcol = (tid & 15) << 2;     // 0..60

#pragma unroll 1
    for (int kc = 0; kc < 2; ++kc) {
        const int k0 = kbase + kc * KC;
        v2f acc2[4][8];
#pragma unroll
        for (int a = 0; a < 4; ++a)
#pragma unroll
            for (int j = 0; j < 8; ++j) acc2[a][j] = (v2f)(0.0f);

#pragma unroll 1
        for (int dc = 0; dc < EMB_DIM / DC; ++dc) {
            __syncthreads();
            // z tile: 16 d-rows x 64 positions, one float4 per thread
            {
                float4 v = *(const float4*)(zb + (size_t)(dc * DC + zrow) * HW + zcol);
                *(float4*)(z_buf + zrow * MT + zcol) = v;
            }
            // c tile transposed: 256 codes x 16 dims, 4 float4 per thread
#pragma unroll
            for (int pass = 0; pass < 4; ++pass) {
                int idx = pass * 256 + tid;
                int kk  = idx >> 2;            // 0..255
                int seg = idx & 3;             // float4 # within the 16-d span
                float4 v = *(const float4*)(cb + (size_t)(k0 + kk) * EMB_DIM + dc * DC + seg * 4);
                c_buf[(seg * 4 + 0) * CPAD + kk] = v.x;
                c_buf[(seg * 4 + 1) * CPAD + kk] = v.y;
                c_buf[(seg * 4 + 2) * CPAD + kk] = v.z;
                c_buf[(seg * 4 + 3) * CPAD + kk] = v.w;
            }
            __syncthreads();

#pragma unroll 4
            for (int d = 0; d < DC; ++d) {
                float4 za = *(const float4*)(z_buf + d * MT + ty * 4);
                float zf[4] = {za.x, za.y, za.z, za.w};
                v2f cf2[8];
#pragma unroll
                for (int j = 0; j < 4; ++j) {
                    float4 cv = *(const float4*)(c_buf + d * CPAD + j * 64 + tx * 4);
                    cf2[j * 2 + 0] = (v2f){cv.x, cv.y};
                    cf2[j * 2 + 1] = (v2f){cv.z, cv.w};
                }
#pragma unroll
                for (int a = 0; a < 4; ++a) {
                    v2f zz = (v2f){zf[a], zf[a]};
#pragma unroll
                    for (int j = 0; j < 8; ++j)
                        acc2[a][j] = __builtin_elementwise_fma(zz, cf2[j], acc2[a][j]);
                }
            }
        }
        // fold chunk into running argmin with reference rounding
        float c2[16];
#pragma unroll
        for (int j = 0; j < 4; ++j)
#pragma unroll
            for (int c = 0; c < 4; ++c)
                c2[j * 4 + c] = cn[k0 + j * 64 + tx * 4 + c];
#pragma unroll
        for (int a = 0; a < 4; ++a) {
#pragma unroll
            for (int j = 0; j < 4; ++j) {
#pragma unroll
                for (int c = 0; c < 4; ++c) {      // kg ascending per thread
                    int kg = k0 + j * 64 + tx * 4 + c;
                    float dot = acc2[a][j * 2 + (c >> 1)][c & 1];
                    float t1 = __fadd_rn(z2[a], c2[j * 4 + c]);
                    float s  = __fadd_rn(t1, __fmul_rn(-2.0f, dot));
                    if (s < minv[a]) { minv[a] = s; mini[a] = kg; }  // strict <
                }
            }
        }
    }

    // cross-tx reduction (reuse c_buf), ties -> smallest index
    __syncthreads();
    float* rv = c_buf;
    int*   ri = (int*)(c_buf + 1024);
#pragma unroll
    for (int a = 0; a < 4; ++a) {
        int m = ty * 4 + a;
        rv[m * 16 + tx] = minv[a];
        ri[m * 16 + tx] = mini[a];
    }
    __syncthreads();
    if (tid < MT) {
        int m = tid;
        float bv = rv[m * 16];
        int   bi = ri[m * 16];
#pragma unroll
        for (int j = 1; j < 16; ++j) {
            float v  = rv[m * 16 + j];
            int   i2 = ri[m * 16 + j];
            if (v < bv || (v == bv && i2 < bi)) { bv = v; bi = i2; }
        }
        int n = b * HW + p0 + m;
        out[2 * n + kh] = bv;                         // partial value
        ((int*)out)[65536 + 2 * n + kh] = bi;         // partial index
    }
}

// ---------------------------------------------------------------------------
// K1b: merge the two k-half partials. Half-0 indices < half-1 indices, so a
// tie keeps half 0 (numpy first-occurrence).
__global__ __launch_bounds__(256) void k_merge(float* __restrict__ out) {
    int n = blockIdx.x * 256 + threadIdx.x;
    float v0 = out[2 * n], v1 = out[2 * n + 1];
    const int* pi = (const int*)out + 65536;
    int i0 = pi[2 * n], i1 = pi[2 * n + 1];
    out[IDX_OFF + n] = (float)((v1 < v0) ? i1 : i0);
}

// ---------------------------------------------------------------------------
// K2: gather z_q, straight-through out = fl(z + fl(z_q - z)), loss partial sums
__global__ __launch_bounds__(256) void k_gather(const float* __restrict__ z,
                                                const float* __restrict__ cb,
                                                float* __restrict__ out,
                                                float* __restrict__ ws) {
    __shared__ int   s_idx[64];
    __shared__ float s_red[4];
    const int tid = threadIdx.x;
    const int b  = blockIdx.x >> 4;
    const int p0 = (blockIdx.x & 15) * 64;

    if (tid < 64)
        s_idx[tid] = (int)out[IDX_OFF + (size_t)b * HW + p0 + tid];
    __syncthreads();

    const int p = tid & 63;
    const int cbase = tid >> 6;
    const int r = s_idx[p];
    const float* zrow = z   + (size_t)b * EMB_DIM * HW + p0 + p;
    float*       orow = out + (size_t)b * EMB_DIM * HW + p0 + p;
    const float* crow = cb  + (size_t)r * EMB_DIM;

    float acc = 0.0f;
#pragma unroll 4
    for (int it = 0; it < 64; ++it) {
        int c = it * 4 + cbase;
        float zq = crow[c];
        float zv = zrow[(size_t)c * HW];
        float d  = zq - zv;
        orow[(size_t)c * HW] = zv + d;
        acc += d * d;
    }
#pragma unroll
    for (int off = 32; off > 0; off >>= 1) acc += __shfl_down(acc, off, 64);
    if ((tid & 63) == 0) s_red[tid >> 6] = acc;
    __syncthreads();
    if (tid == 0) atomicAdd(ws, s_red[0] + s_red[1] + s_red[2] + s_red[3]);
}

// ---------------------------------------------------------------------------
__global__ void k_final(const float* __restrict__ ws, float* __restrict__ out) {
    out[LOSS_OFF] = 1.25f * (ws[0] * (1.0f / 8388608.0f));
}

// ---------------------------------------------------------------------------
extern "C" void kernel_launch(void* const* d_in, const int* in_sizes, int n_in,
                              void* d_out, int out_size, void* d_ws, size_t ws_size,
                              hipStream_t stream) {
    const float* z  = (const float*)d_in[0];
    const float* cb = (const float*)d_in[1];
    float* out = (float*)d_out;
    float* ws  = (float*)d_ws;

    k_cnorm <<<NUM_EMB / 256, 256, 0, stream>>>(cb, ws);
    k_znorm <<<BATCH * HW / 256, 256, 0, stream>>>(z, ws);
    k_argmin<<<dim3(HW / MT, BATCH, 2), 256, 0, stream>>>(z, cb, ws, out);
    k_merge <<<BATCH * HW / 256, 256, 0, stream>>>(out);
    k_gather<<<BATCH * (HW / 64), 256, 0, stream>>>(z, cb, out, ws);
    k_final <<<1, 1, 0, stream>>>(ws, out);
}

// Round 4
// 323.515 us; speedup vs baseline: 1.5299x; 1.0894x over previous
//
#include <hip/hip_runtime.h>

// Problem constants
#define NUM_EMB 1024
#define EMB_DIM 256
#define BATCH   32
#define HW      1024
#define Z_ELEMS (BATCH*EMB_DIM*HW)   // 8388608
#define LOSS_OFF Z_ELEMS
#define IDX_OFF (Z_ELEMS+1)

// ws layout: float[0] loss acc, uint[1] ticket, floats [16..1040) cnorm,
// [2048..34816) znorm; packed u64 argmin partials at byte 262144 (if ws fits).
#define WS_CNORM_OFF 16
#define WS_ZNORM_OFF 2048
#define WS_PACKED_BYTE_OFF 262144
#define WS_NEEDED (WS_PACKED_BYTE_OFF + 32768*8)

typedef float v2f __attribute__((ext_vector_type(2)));

// ---------------------------------------------------------------------------
// K0: fused prep. Blocks 0..3: cnorm[k] (numpy pairwise tree, fp32, squares
// rounded separately, no contraction). Blocks 4..131: znorm[n] (same tree) +
// init packed[n] = u64max. Thread 0 zeroes loss acc + ticket.
__global__ __launch_bounds__(256) void k_prep(const float* __restrict__ z,
                                              const float* __restrict__ cb,
                                              float* __restrict__ ws,
                                              unsigned long long* __restrict__ packed) {
    int gid = blockIdx.x * 256 + threadIdx.x;
    if (gid == 0) { ws[0] = 0.0f; ((unsigned int*)ws)[1] = 0u; }
    if (blockIdx.x < 4) {
        int k = gid;
        const float* row = cb + (size_t)k * EMB_DIM;
        float half[2];
#pragma unroll
        for (int h = 0; h < 2; ++h) {
            const float* a = row + h * 128;
            float r[8];
#pragma unroll
            for (int j = 0; j < 8; ++j) r[j] = __fmul_rn(a[j], a[j]);
            for (int i = 8; i < 128; i += 8)
#pragma unroll
                for (int j = 0; j < 8; ++j)
                    r[j] = __fadd_rn(r[j], __fmul_rn(a[i + j], a[i + j]));
            half[h] = __fadd_rn(__fadd_rn(__fadd_rn(r[0], r[1]), __fadd_rn(r[2], r[3])),
                                __fadd_rn(__fadd_rn(r[4], r[5]), __fadd_rn(r[6], r[7])));
        }
        ws[WS_CNORM_OFF + k] = __fadd_rn(half[0], half[1]);
    } else {
        int n = gid - 1024;
        packed[n] = 0xFFFFFFFFFFFFFFFFull;
        int b = n >> 10, p = n & 1023;
        const float* base = z + (size_t)b * EMB_DIM * HW + p;
        float half[2];
#pragma unroll
        for (int h = 0; h < 2; ++h) {
            float r[8];
#pragma unroll
            for (int j = 0; j < 8; ++j) {
                float v = base[(size_t)(h * 128 + j) * HW];
                r[j] = __fmul_rn(v, v);
            }
            for (int i = 8; i < 128; i += 8)
#pragma unroll
                for (int j = 0; j < 8; ++j) {
                    float v = base[(size_t)(h * 128 + i + j) * HW];
                    r[j] = __fadd_rn(r[j], __fmul_rn(v, v));
                }
            half[h] = __fadd_rn(__fadd_rn(__fadd_rn(r[0], r[1]), __fadd_rn(r[2], r[3])),
                                __fadd_rn(__fadd_rn(r[4], r[5]), __fadd_rn(r[6], r[7])));
        }
        ws[WS_ZNORM_OFF + n] = __fadd_rn(half[0], half[1]);
    }
}

// ---------------------------------------------------------------------------
// K1: distance argmin over a 512-code half, reference fp32 rounding:
//   d = fl( fl(z2 + c2) - fl(2*dot) ), dot = serial ascending-d fma per (n,k).
// Inner product via inline-asm v_pk_fma_f32 (two independent k-chains per op;
// op_sel broadcasts the z scalar from a pair -> no v_mov). Result folded into
// a packed (val_bits<<32)|idx u64; global atomicMin merges block/half partials
// (distances ~256 > 0, so fp32 bit pattern is order-monotone; tie -> min idx).
#define MT 64
#define KC 256
#define DC 16
#define CPAD 260

__global__ __launch_bounds__(256, 4) void k_argmin(const float* __restrict__ z,
                                                   const float* __restrict__ cb,
                                                   const float* __restrict__ ws,
                                                   unsigned long long* __restrict__ packed) {
    __shared__ __attribute__((aligned(16))) float z_buf[DC * MT];    // 4 KB
    __shared__ __attribute__((aligned(16))) float c_buf[DC * CPAD];  // 16.6 KB

    const int tid = threadIdx.x;
    const int tx = tid & 15;
    const int ty = tid >> 4;          // 0..15
    const int b  = blockIdx.y;
    const int p0 = blockIdx.x * MT;
    const int kbase = blockIdx.z * 512;

    const float* zb = z + (size_t)b * EMB_DIM * HW + p0;
    const float* cn = ws + WS_CNORM_OFF;
    const float* zn = ws + WS_ZNORM_OFF + b * HW + p0;

    float z2[4];
#pragma unroll
    for (int a = 0; a < 4; ++a) z2[a] = zn[ty * 4 + a];

    float minv[4];
    int   mini[4];
#pragma unroll
    for (int a = 0; a < 4; ++a) { minv[a] = 3.402823466e+38f; mini[a] = 0; }

    const int zrow = tid >> 4;            // 0..15
    const int zcol = (tid & 15) << 2;     // 0..60

#pragma unroll 1
    for (int kc = 0; kc < 2; ++kc) {
        const int k0 = kbase + kc * KC;
        v2f acc2[4][8];
#pragma unroll
        for (int a = 0; a < 4; ++a)
#pragma unroll
            for (int j = 0; j < 8; ++j) acc2[a][j] = (v2f)(0.0f);

#pragma unroll 1
        for (int dc = 0; dc < EMB_DIM / DC; ++dc) {
            __syncthreads();
            {   // z tile: 16 d-rows x 64 positions, one float4 per thread
                float4 v = *(const float4*)(zb + (size_t)(dc * DC + zrow) * HW + zcol);
                *(float4*)(z_buf + zrow * MT + zcol) = v;
            }
#pragma unroll
            for (int pass = 0; pass < 4; ++pass) {   // c tile transposed
                int idx = pass * 256 + tid;
                int kk  = idx >> 2;
                int seg = idx & 3;
                float4 v = *(const float4*)(cb + (size_t)(k0 + kk) * EMB_DIM + dc * DC + seg * 4);
                c_buf[(seg * 4 + 0) * CPAD + kk] = v.x;
                c_buf[(seg * 4 + 1) * CPAD + kk] = v.y;
                c_buf[(seg * 4 + 2) * CPAD + kk] = v.z;
                c_buf[(seg * 4 + 3) * CPAD + kk] = v.w;
            }
            __syncthreads();

#pragma unroll 2
            for (int d = 0; d < DC; ++d) {
                v2f za01 = *(const v2f*)(z_buf + d * MT + ty * 4);
                v2f za23 = *(const v2f*)(z_buf + d * MT + ty * 4 + 2);
                v2f cf2[8];
#pragma unroll
                for (int j = 0; j < 4; ++j) {
                    float4 cv = *(const float4*)(c_buf + d * CPAD + j * 64 + tx * 4);
                    cf2[j * 2 + 0] = (v2f){cv.x, cv.y};
                    cf2[j * 2 + 1] = (v2f){cv.z, cv.w};
                }
#pragma unroll
                for (int j = 0; j < 8; ++j) {
                    // a=0: m=ty*4+0 (broadcast lo of za01); a=1: hi of za01; etc.
                    asm("v_pk_fma_f32 %0, %1, %2, %0 op_sel:[0,0,0] op_sel_hi:[0,1,1]"
                        : "+v"(acc2[0][j]) : "v"(za01), "v"(cf2[j]));
                    asm("v_pk_fma_f32 %0, %1, %2, %0 op_sel:[1,0,0] op_sel_hi:[1,1,1]"
                        : "+v"(acc2[1][j]) : "v"(za01), "v"(cf2[j]));
                    asm("v_pk_fma_f32 %0, %1, %2, %0 op_sel:[0,0,0] op_sel_hi:[0,1,1]"
                        : "+v"(acc2[2][j]) : "v"(za23), "v"(cf2[j]));
                    asm("v_pk_fma_f32 %0, %1, %2, %0 op_sel:[1,0,0] op_sel_hi:[1,1,1]"
                        : "+v"(acc2[3][j]) : "v"(za23), "v"(cf2[j]));
                }
            }
        }
        // fold chunk into running argmin with reference rounding
        float c2[16];
#pragma unroll
        for (int j = 0; j < 4; ++j)
#pragma unroll
            for (int c = 0; c < 4; ++c)
                c2[j * 4 + c] = cn[k0 + j * 64 + tx * 4 + c];
#pragma unroll
        for (int a = 0; a < 4; ++a) {
#pragma unroll
            for (int j = 0; j < 4; ++j) {
#pragma unroll
                for (int c = 0; c < 4; ++c) {      // kg ascending per thread
                    int kg = k0 + j * 64 + tx * 4 + c;
                    float dot = acc2[a][j * 2 + (c >> 1)][c & 1];
                    float t1 = __fadd_rn(z2[a], c2[j * 4 + c]);
                    float s  = __fadd_rn(t1, __fmul_rn(-2.0f, dot));
                    if (s < minv[a]) { minv[a] = s; mini[a] = kg; }  // strict <
                }
            }
        }
    }

    // cross-tx reduction (reuse c_buf), ties -> smallest index
    __syncthreads();
    float* rv = c_buf;
    int*   ri = (int*)(c_buf + 1024);
#pragma unroll
    for (int a = 0; a < 4; ++a) {
        int m = ty * 4 + a;
        rv[m * 16 + tx] = minv[a];
        ri[m * 16 + tx] = mini[a];
    }
    __syncthreads();
    if (tid < MT) {
        int m = tid;
        float bv = rv[m * 16];
        int   bi = ri[m * 16];
#pragma unroll
        for (int j = 1; j < 16; ++j) {
            float v  = rv[m * 16 + j];
            int   i2 = ri[m * 16 + j];
            if (v < bv || (v == bv && i2 < bi)) { bv = v; bi = i2; }
        }
        int n = b * HW + p0 + m;
        unsigned long long pk = ((unsigned long long)__float_as_uint(bv) << 32)
                                | (unsigned long long)(unsigned)bi;
        atomicMin(&packed[n], pk);
    }
}

// ---------------------------------------------------------------------------
// K1b (fallback only, when packed lives in out's z-region): extract indices.
__global__ __launch_bounds__(256) void k_merge(const unsigned long long* __restrict__ packed,
                                               float* __restrict__ out) {
    int n = blockIdx.x * 256 + threadIdx.x;
    out[IDX_OFF + n] = (float)(int)(unsigned)(packed[n] & 0xFFFFFFFFull);
}

// ---------------------------------------------------------------------------
// K2: gather z_q, straight-through out = fl(z + fl(z_q - z)), loss partials;
// fused index extraction (main path) + fused final scale via ticket counter.
__global__ __launch_bounds__(256) void k_gather(const float* __restrict__ z,
                                                const float* __restrict__ cb,
                                                float* __restrict__ out,
                                                float* __restrict__ ws,
                                                const unsigned long long* __restrict__ packed,
                                                int fused_idx) {
    __shared__ int   s_idx[64];
    __shared__ float s_red[4];
    const int tid = threadIdx.x;
    const int b  = blockIdx.x >> 4;
    const int p0 = (blockIdx.x & 15) * 64;

    if (tid < 64) {
        int n = b * HW + p0 + tid;
        int bi;
        if (fused_idx) {
            bi = (int)(unsigned)(packed[n] & 0xFFFFFFFFull);
            out[IDX_OFF + n] = (float)bi;
        } else {
            bi = (int)out[IDX_OFF + n];
        }
        s_idx[tid] = bi;
    }
    __syncthreads();

    const int p = tid & 63;
    const int cbase = tid >> 6;
    const int r = s_idx[p];
    const float* zrow = z   + (size_t)b * EMB_DIM * HW + p0 + p;
    float*       orow = out + (size_t)b * EMB_DIM * HW + p0 + p;
    const float* crow = cb  + (size_t)r * EMB_DIM;

    float acc = 0.0f;
#pragma unroll 4
    for (int it = 0; it < 64; ++it) {
        int c = it * 4 + cbase;
        float zq = crow[c];
        float zv = zrow[(size_t)c * HW];
        float d  = zq - zv;
        orow[(size_t)c * HW] = zv + d;
        acc += d * d;
    }
#pragma unroll
    for (int off = 32; off > 0; off >>= 1) acc += __shfl_down(acc, off, 64);
    if ((tid & 63) == 0) s_red[tid >> 6] = acc;
    __syncthreads();
    if (tid == 0) {
        atomicAdd(ws, s_red[0] + s_red[1] + s_red[2] + s_red[3]);
        __threadfence();
        unsigned old = atomicAdd((unsigned int*)ws + 1, 1u);
        if (old == 511u) {   // last block: all 512 loss adds are visible
            float total = atomicAdd(ws, 0.0f);
            out[LOSS_OFF] = 1.25f * (total * (1.0f / 8388608.0f));
        }
    }
}

// ---------------------------------------------------------------------------
extern "C" void kernel_launch(void* const* d_in, const int* in_sizes, int n_in,
                              void* d_out, int out_size, void* d_ws, size_t ws_size,
                              hipStream_t stream) {
    const float* z  = (const float*)d_in[0];
    const float* cb = (const float*)d_in[1];
    float* out = (float*)d_out;
    float* ws  = (float*)d_ws;

    const bool big_ws = (ws_size >= (size_t)WS_NEEDED);
    unsigned long long* packed = big_ws
        ? (unsigned long long*)((char*)d_ws + WS_PACKED_BYTE_OFF)
        : (unsigned long long*)d_out;   // stage in out's z-region, merge before gather

    k_prep  <<<132, 256, 0, stream>>>(z, cb, ws, packed);
    k_argmin<<<dim3(HW / MT, BATCH, 2), 256, 0, stream>>>(z, cb, ws, packed);
    if (!big_ws)
        k_merge<<<BATCH * HW / 256, 256, 0, stream>>>(packed, out);
    k_gather<<<BATCH * (HW / 64), 256, 0, stream>>>(z, cb, out, ws, packed, big_ws ? 1 : 0);
}